// Round 2
// baseline (4892.739 us; speedup 1.0000x reference)
//
#include <hip/hip_runtime.h>
#include <hip/hip_bf16.h>
#include <math.h>

// Problem constants
#define TT 64
#define BB 32
#define CIN 4
#define HW 84
#define HID 256
#define NA 12
#define FEAT 1152
#define NB 2048           // T*B
#define G3 768            // 3*HID

typedef __hip_bfloat16 bf16;

static __device__ __forceinline__ float bf2f(bf16 v) { return __bfloat162float(v); }
static __device__ __forceinline__ bf16 f2bf(float v) { return __float2bfloat16(v); }

// ---------------- prep: transpose W_ih, W_hh; fold biases ----------------
__global__ __launch_bounds__(256) void prep_kernel(
    const float* __restrict__ W_ih, const float* __restrict__ W_hh,
    const float* __restrict__ b_ih, const float* __restrict__ b_hh,
    float* __restrict__ wihT,   // [1152][768]
    float* __restrict__ whhT,   // [256][768]
    float* __restrict__ biasg)  // [768] = b_ih + b_hh(first 512 only)
{
    int i = blockIdx.x * 256 + threadIdx.x;
    if (i < FEAT * G3) {
        int k = i / G3, g = i % G3;
        wihT[i] = W_ih[(size_t)g * FEAT + k];
    }
    if (i < HID * G3) {
        int k = i / G3, g = i % G3;
        whhT[i] = W_hh[(size_t)g * HID + k];
    }
    if (i < G3) {
        biasg[i] = b_ih[i] + (i < 2 * HID ? b_hh[i] : 0.0f);
    }
}

// ---------------- fused conv1+conv2 (per image quadrant) ----------------
// in: [2048,4,84,84] f32 ; out x2: [2048,21,21,32] bf16 (channel-last)
__global__ __launch_bounds__(256) void conv12_kernel(
    const float* __restrict__ in,
    const float* __restrict__ w1, const float* __restrict__ b1,
    const float* __restrict__ w2, const float* __restrict__ b2,
    bf16* __restrict__ x2)
{
    __shared__ float w1s[9 * 4 * 32];     // [kk][ci][c1]
    __shared__ bf16  w2s[9 * 32 * 32];    // [kk][ci][c2]
    __shared__ bf16  x1s[23 * 23 * 32];   // [ty][tx][c]

    int nq = blockIdx.x;
    int n = nq >> 2, q = nq & 3;
    int qy = q >> 1, qx = q & 1;
    int oy0 = qy * 11, ox0 = qx * 11;
    int ny = qy ? 10 : 11, nx = qx ? 10 : 11;
    int tid = threadIdx.x;

    // weights -> LDS
    for (int i = tid; i < 9 * 4 * 32; i += 256) {
        int c1 = i & 31, t = i >> 5;      // t = kk*4 + ci
        int kk = t >> 2, ci = t & 3;
        w1s[i] = w1[c1 * 36 + ci * 9 + kk];
    }
    for (int i = tid; i < 9 * 32 * 32; i += 256) {
        int c2 = i & 31, t = i >> 5;      // t = kk*32 + ci
        int kk = t >> 5, ci = t & 31;
        w2s[i] = f2bf(w2[c2 * 288 + ci * 9 + kk]);
    }
    __syncthreads();

    // phase 1: conv1 tile (x1 coords y = 2*oy0-1+ty)
    int th = 2 * ny + 1, tw = 2 * nx + 1;
    int npix = th * tw;
    const float* inb = in + (size_t)n * (CIN * HW * HW);
    for (int i = tid; i < npix * 32; i += 256) {
        int c1 = i & 31, p = i >> 5;
        int ty = p / tw, tx = p % tw;
        int y = 2 * oy0 - 1 + ty, x = 2 * ox0 - 1 + tx;
        float v = 0.0f;
        if (y >= 0 && x >= 0) {  // y,x <= 41 guaranteed
            float acc = b1[c1];
            for (int kh = 0; kh < 3; kh++) {
                int ih = 2 * y - 1 + kh;
                if ((unsigned)ih >= (unsigned)HW) continue;
                for (int kw = 0; kw < 3; kw++) {
                    int iw = 2 * x - 1 + kw;
                    if ((unsigned)iw >= (unsigned)HW) continue;
                    int kk = kh * 3 + kw;
                    for (int ci = 0; ci < 4; ci++)
                        acc += inb[ci * 7056 + ih * 84 + iw] * w1s[(kk * 4 + ci) * 32 + c1];
                }
            }
            v = acc > 0.0f ? acc : expm1f(acc);
        }
        x1s[(ty * tw + tx) * 32 + c1] = f2bf(v);
    }
    __syncthreads();

    // phase 2: conv2 on the LDS tile
    for (int i = tid; i < ny * nx * 32; i += 256) {
        int c2 = i & 31, p = i >> 5;
        int oy = p / nx, ox = p % nx;
        float acc = b2[c2];
        for (int kh = 0; kh < 3; kh++)
            for (int kw = 0; kw < 3; kw++) {
                int kk = kh * 3 + kw;
                int base = ((2 * oy + kh) * tw + 2 * ox + kw) * 32;
                for (int ci = 0; ci < 32; ci++)
                    acc += bf2f(x1s[base + ci]) * bf2f(w2s[(kk * 32 + ci) * 32 + c2]);
            }
        float v = acc > 0.0f ? acc : expm1f(acc);
        int gy = oy0 + oy, gx = ox0 + ox;
        x2[((size_t)n * 441 + gy * 21 + gx) * 32 + c2] = f2bf(v);
    }
}

// ---------------- conv3: [2048,21,21,32] -> [2048,11,11,32] ----------------
__global__ __launch_bounds__(256) void conv3_kernel(
    const bf16* __restrict__ x2, const float* __restrict__ w3,
    const float* __restrict__ b3, bf16* __restrict__ x3)
{
    __shared__ bf16 xs[441 * 32];
    __shared__ bf16 ws[9 * 32 * 32];   // [kk][ci][c]
    int n = blockIdx.x, tid = threadIdx.x;
    const bf16* src = x2 + (size_t)n * 441 * 32;
    for (int i = tid; i < 441 * 32 / 2; i += 256)
        ((unsigned int*)xs)[i] = ((const unsigned int*)src)[i];
    for (int i = tid; i < 9 * 32 * 32; i += 256) {
        int c = i & 31, t = i >> 5;
        int kk = t >> 5, ci = t & 31;
        ws[i] = f2bf(w3[c * 288 + ci * 9 + kk]);
    }
    __syncthreads();
    for (int i = tid; i < 121 * 32; i += 256) {
        int c = i & 31, p = i >> 5;
        int oy = p / 11, ox = p % 11;
        float acc = b3[c];
        for (int kh = 0; kh < 3; kh++) {
            int y = 2 * oy - 1 + kh;
            if ((unsigned)y >= 21u) continue;
            for (int kw = 0; kw < 3; kw++) {
                int x = 2 * ox - 1 + kw;
                if ((unsigned)x >= 21u) continue;
                int kk = kh * 3 + kw;
                int base = (y * 21 + x) * 32;
                for (int ci = 0; ci < 32; ci++)
                    acc += bf2f(xs[base + ci]) * bf2f(ws[(kk * 32 + ci) * 32 + c]);
            }
        }
        float v = acc > 0.0f ? acc : expm1f(acc);
        x3[((size_t)n * 121 + p) * 32 + c] = f2bf(v);
    }
}

// ---------------- conv4: [2048,11,11,32] -> x4 NCHW-flat [2048,1152] ----------------
__global__ __launch_bounds__(256) void conv4_kernel(
    const bf16* __restrict__ x3, const float* __restrict__ w4,
    const float* __restrict__ b4, bf16* __restrict__ x4)
{
    __shared__ bf16 xs[121 * 32];
    __shared__ bf16 ws[9 * 32 * 32];
    int n = blockIdx.x, tid = threadIdx.x;
    const bf16* src = x3 + (size_t)n * 121 * 32;
    for (int i = tid; i < 121 * 32 / 2; i += 256)
        ((unsigned int*)xs)[i] = ((const unsigned int*)src)[i];
    for (int i = tid; i < 9 * 32 * 32; i += 256) {
        int c = i & 31, t = i >> 5;
        int kk = t >> 5, ci = t & 31;
        ws[i] = f2bf(w4[c * 288 + ci * 9 + kk]);
    }
    __syncthreads();
    for (int i = tid; i < 36 * 32; i += 256) {
        int c = i & 31, p = i >> 5;
        int oy = p / 6, ox = p % 6;
        float acc = b4[c];
        for (int kh = 0; kh < 3; kh++) {
            int y = 2 * oy - 1 + kh;
            if ((unsigned)y >= 11u) continue;
            for (int kw = 0; kw < 3; kw++) {
                int x = 2 * ox - 1 + kw;
                if ((unsigned)x >= 11u) continue;
                int kk = kh * 3 + kw;
                int base = (y * 11 + x) * 32;
                for (int ci = 0; ci < 32; ci++)
                    acc += bf2f(xs[base + ci]) * bf2f(ws[(kk * 32 + ci) * 32 + c]);
            }
        }
        float v = acc > 0.0f ? acc : expm1f(acc);
        // feature order = NCHW flatten: c*36 + p
        x4[(size_t)n * FEAT + c * 36 + p] = f2bf(v);
    }
}

// ---------------- GI = x4 @ W_ih^T + (b_ih + b_hh[r,z]) ----------------
// x4: [2048,1152] bf16 ; wihT: [1152][768] f32 ; GI: [2048,768] f32
__global__ __launch_bounds__(256) void gemm_gi_kernel(
    const bf16* __restrict__ X, const float* __restrict__ Bm,
    const float* __restrict__ biasg, float* __restrict__ GI)
{
    __shared__ float As[16][68];
    __shared__ float Bs[16][68];
    int bm = blockIdx.x, bn = blockIdx.y;
    int tid = threadIdx.x;
    int tx = tid & 15, ty = tid >> 4;
    int m0 = bm * 64, n0 = bn * 64;
    float acc[4][4] = {};
    for (int k0 = 0; k0 < FEAT; k0 += 16) {
        {   // A tile: 64 rows x 16 k
            int m = tid >> 2, kq = (tid & 3) * 4;
            const bf16* ap = X + (size_t)(m0 + m) * FEAT + k0 + kq;
            uint2 d = *(const uint2*)ap;
            ushort u0 = (ushort)(d.x & 0xffff), u1 = (ushort)(d.x >> 16);
            ushort u2 = (ushort)(d.y & 0xffff), u3 = (ushort)(d.y >> 16);
            As[kq + 0][m] = __uint_as_float((unsigned)u0 << 16);
            As[kq + 1][m] = __uint_as_float((unsigned)u1 << 16);
            As[kq + 2][m] = __uint_as_float((unsigned)u2 << 16);
            As[kq + 3][m] = __uint_as_float((unsigned)u3 << 16);
        }
        {   // B tile: 16 k x 64 cols
            int g = tid & 63, kb = tid >> 6;
            for (int j = 0; j < 4; j++) {
                int k = kb * 4 + j;
                Bs[k][g] = Bm[(size_t)(k0 + k) * G3 + n0 + g];
            }
        }
        __syncthreads();
        for (int kk = 0; kk < 16; kk++) {
            float4 a = *(const float4*)&As[kk][ty * 4];
            float4 b = *(const float4*)&Bs[kk][tx * 4];
            float av[4] = {a.x, a.y, a.z, a.w};
            float bv[4] = {b.x, b.y, b.z, b.w};
            for (int i = 0; i < 4; i++)
                for (int j = 0; j < 4; j++)
                    acc[i][j] += av[i] * bv[j];
        }
        __syncthreads();
    }
    for (int i = 0; i < 4; i++)
        for (int j = 0; j < 4; j++) {
            int m = m0 + ty * 4 + i, g = n0 + tx * 4 + j;
            GI[(size_t)m * G3 + g] = acc[i][j] + biasg[g];
        }
}

// ---------------- GRU scan: one block per batch row ----------------
__global__ __launch_bounds__(256) void scan_kernel(
    const float* __restrict__ GI, const float* __restrict__ whhT,
    const float* __restrict__ b_hh, const float* __restrict__ rnn_in,
    const float* __restrict__ mask, float* __restrict__ H)
{
    __shared__ float hs[HID];
    int b = blockIdx.x, j = threadIdx.x;
    float h = rnn_in[b * HID + j];
    float bhn = b_hh[2 * HID + j];
    for (int t = 0; t < TT; t++) {
        float m = mask[t * BB + b];
        h *= m;
        hs[j] = h;
        __syncthreads();
        float ar = 0.f, az = 0.f, an = 0.f;
        for (int k = 0; k < HID; k++) {
            float hk = hs[k];
            const float* wp = whhT + k * G3 + j;
            ar += hk * wp[0];
            az += hk * wp[HID];
            an += hk * wp[2 * HID];
        }
        int row = t * BB + b;
        const float* gp = GI + (size_t)row * G3 + j;
        float r = 1.0f / (1.0f + expf(-(gp[0] + ar)));
        float z = 1.0f / (1.0f + expf(-(gp[HID] + az)));
        float pre = gp[2 * HID] + r * (an + bhn);
        pre = fminf(15.0f, fmaxf(-15.0f, pre));
        float e = expf(2.0f * pre);
        float nn = (e - 1.0f) / (e + 1.0f);
        h = (1.0f - z) * nn + z * h;
        H[(size_t)row * HID + j] = h;
        __syncthreads();
    }
}

// ---------------- heads: v, actions, logp_a, ent (float32 out!) ----------------
__global__ __launch_bounds__(256) void heads_kernel(
    const float* __restrict__ H, const int* __restrict__ actions,
    const float* __restrict__ Wc, const float* __restrict__ bc,
    const float* __restrict__ Wa, const float* __restrict__ ba,
    float* __restrict__ out)
{
    int r = blockIdx.x * 256 + threadIdx.x;
    if (r >= NB) return;
    const float* h = H + (size_t)r * HID;
    float v = bc[0];
    for (int k = 0; k < HID; k++) v += h[k] * Wc[k];
    float lg[NA];
    for (int a = 0; a < NA; a++) {
        float s = ba[a];
        const float* wa = Wa + a * HID;
        for (int k = 0; k < HID; k++) s += h[k] * wa[k];
        lg[a] = s;
    }
    float mx = lg[0];
    for (int a = 1; a < NA; a++) mx = fmaxf(mx, lg[a]);
    float Z = 0.f;
    for (int a = 0; a < NA; a++) Z += expf(lg[a] - mx);
    float lse = mx + logf(Z);
    int act = actions[r];
    float logp_a = lg[act] - lse;
    float ent = 0.f;
    for (int a = 0; a < NA; a++) {
        float lp = lg[a] - lse;
        ent -= expf(lp) * lp;
    }
    out[r]            = v;
    out[NB + r]       = (float)act;
    out[2 * NB + r]   = logp_a;
    out[3 * NB + r]   = ent;
}

// ---------------- h_final copy (float32 out) ----------------
__global__ __launch_bounds__(256) void hfin_kernel(const float* __restrict__ H, float* __restrict__ out)
{
    int i = blockIdx.x * 256 + threadIdx.x;
    if (i < BB * HID)
        out[4 * NB + i] = H[(size_t)(TT - 1) * BB * HID + i];
}

extern "C" void kernel_launch(void* const* d_in, const int* in_sizes, int n_in,
                              void* d_out, int out_size, void* d_ws, size_t ws_size,
                              hipStream_t stream) {
    const float* inputs = (const float*)d_in[0];
    const float* rnn_in = (const float*)d_in[1];
    const float* mask   = (const float*)d_in[2];
    const int*   actions= (const int*)d_in[3];
    const float* w1 = (const float*)d_in[4];
    const float* b1 = (const float*)d_in[5];
    const float* w2 = (const float*)d_in[6];
    const float* b2 = (const float*)d_in[7];
    const float* w3 = (const float*)d_in[8];
    const float* b3 = (const float*)d_in[9];
    const float* w4 = (const float*)d_in[10];
    const float* b4 = (const float*)d_in[11];
    const float* W_ih = (const float*)d_in[12];
    const float* W_hh = (const float*)d_in[13];
    const float* b_ih = (const float*)d_in[14];
    const float* b_hh = (const float*)d_in[15];
    const float* Wc = (const float*)d_in[16];
    const float* bc = (const float*)d_in[17];
    const float* Wa = (const float*)d_in[18];
    const float* ba = (const float*)d_in[19];
    float* out = (float*)d_out;   // reference outputs are float32/int32 -> float* per harness spec

    char* ws = (char*)d_ws;
    size_t off = 0;
    bf16* x2 = (bf16*)(ws + off);      off += (size_t)NB * 441 * 32 * 2;   // 57,802,752
    bf16* x3 = (bf16*)(ws + off);      off += (size_t)NB * 121 * 32 * 2;   // 15,859,712
    bf16* x4 = (bf16*)(ws + off);      off += (size_t)NB * FEAT * 2;       //  4,718,592
    float* wihT = (float*)(ws + off);  off += (size_t)FEAT * G3 * 4;       //  3,538,944
    float* whhT = (float*)(ws + off);  off += (size_t)HID * G3 * 4;        //    786,432
    float* biasg = (float*)(ws + off); off += 4096;
    float* GI = (float*)(ws + off);    off += (size_t)NB * G3 * 4;         //  6,291,456
    float* H  = (float*)(ws + off);    off += (size_t)NB * HID * 4;        //  2,097,152

    prep_kernel<<<(FEAT * G3 + 255) / 256, 256, 0, stream>>>(W_ih, W_hh, b_ih, b_hh, wihT, whhT, biasg);
    conv12_kernel<<<NB * 4, 256, 0, stream>>>(inputs, w1, b1, w2, b2, x2);
    conv3_kernel<<<NB, 256, 0, stream>>>(x2, w3, b3, x3);
    conv4_kernel<<<NB, 256, 0, stream>>>(x3, w4, b4, x4);
    gemm_gi_kernel<<<dim3(NB / 64, G3 / 64), 256, 0, stream>>>(x4, wihT, biasg, GI);
    scan_kernel<<<BB, HID, 0, stream>>>(GI, whhT, b_hh, rnn_in, mask, H);
    heads_kernel<<<NB / 256, 256, 0, stream>>>(H, actions, Wc, bc, Wa, ba, out);
    hfin_kernel<<<(BB * HID + 255) / 256, 256, 0, stream>>>(H, out);
}

// Round 3
// 1822.038 us; speedup vs baseline: 2.6853x; 2.6853x over previous
//
#include <hip/hip_runtime.h>
#include <hip/hip_bf16.h>
#include <math.h>

#define TT 64
#define BB 32
#define HID 256
#define NA 12
#define FEAT 1152
#define NB 2048           // T*B
#define G3 768            // 3*HID

typedef __hip_bfloat16 bf16;
typedef __attribute__((ext_vector_type(8))) short short8;
typedef __attribute__((ext_vector_type(4))) float f32x4;

static __device__ __forceinline__ float bf2f(bf16 v) { return __bfloat162float(v); }
static __device__ __forceinline__ bf16 f2bf(float v) { return __float2bfloat16(v); }

#define MFMA(a, b, c) __builtin_amdgcn_mfma_f32_16x16x32_bf16((a), (b), (c), 0, 0, 0)

// ============================================================================
// prep: build fragment-ordered bf16 weights once.
// Frag layouts (guide, m89/m91/m120-verified):
//   A: lane l holds A[m=l&15][k=8*(l>>4)+j]
//   B: lane l holds B[k=8*(l>>4)+j][n=l&15]
//   D: lane l reg r holds D[row=4*(l>>4)+r][col=l&15]
// ============================================================================
__global__ __launch_bounds__(256) void prep_kernel(
    const float* __restrict__ w1, const float* __restrict__ w2,
    const float* __restrict__ w3, const float* __restrict__ w4,
    const float* __restrict__ W_ih, const float* __restrict__ W_hh,
    const float* __restrict__ b_ih, const float* __restrict__ b_hh,
    bf16* __restrict__ wB1, bf16* __restrict__ wB2,
    bf16* __restrict__ wB3, bf16* __restrict__ wB4,
    bf16* __restrict__ wihF, bf16* __restrict__ whhB, float* __restrict__ biasg)
{
    int i = blockIdx.x * 256 + threadIdx.x;
    if (i < 2048) {              // wB1[nt][ch][lane][j], K=36 padded to 64
        int j = i & 7, l = (i >> 3) & 63, rest = i >> 9;
        int ch = rest & 1, nt = rest >> 1;
        int k = ch * 32 + 8 * (l >> 4) + j;          // k = kk*4 + ci
        int co = nt * 16 + (l & 15);
        wB1[i] = f2bf(k < 36 ? w1[co * 36 + (k & 3) * 9 + (k >> 2)] : 0.0f);
    }
    if (i < 9216) {              // wB2/3/4[nt][kk][lane][j], k = kk*32 + ci
        int j = i & 7, l = (i >> 3) & 63, rest = i >> 9;
        int kk = rest % 9, nt = rest / 9;
        int ci = 8 * (l >> 4) + j, co = nt * 16 + (l & 15);
        wB2[i] = f2bf(w2[co * 288 + ci * 9 + kk]);
        wB3[i] = f2bf(w3[co * 288 + ci * 9 + kk]);
        wB4[i] = f2bf(w4[co * 288 + ci * 9 + kk]);
    }
    if (i < 884736) {            // wihF[ch(36)][st(48)][lane][j]
        int j = i & 7, l = (i >> 3) & 63, rest = i >> 9;
        int st = rest % 48, ch = rest / 48;
        int k = ch * 32 + 8 * (l >> 4) + j, n = st * 16 + (l & 15);
        wihF[i] = f2bf(W_ih[(size_t)n * FEAT + k]);
    }
    if (i < 196608) {            // whhB[k][768] (transposed, bf16)
        int k = i / G3, g = i % G3;
        whhB[i] = f2bf(W_hh[(size_t)g * HID + k]);
    }
    if (i < G3) biasg[i] = b_ih[i] + (i < 2 * HID ? b_hh[i] : 0.0f);
}

// ============================================================================
// conv1: [CH,4,84,84] f32 -> x1 [CH,42,42,32] bf16 channel-last. K=36 pad 64.
// Stage input rows to LDS channel-last, im2col to A, 2-chunk MFMA.
// ============================================================================
__global__ __launch_bounds__(256) void conv1_kernel(
    const float* __restrict__ in, int n0,
    const bf16* __restrict__ wB1g, const float* __restrict__ b1,
    bf16* __restrict__ x1)
{
    __shared__ bf16 ins[7 * 84 * 4];   // [r][x][ci]
    __shared__ bf16 A[64 * 72];        // KP1 = 72 (64 + 8 pad)
    __shared__ bf16 wBs[2048];
    int tid = threadIdx.x;
    int nl = blockIdx.x / 28, blk = blockIdx.x % 28;
    int n = n0 + nl;
    int p0 = blk * 64;
    int oy_lo = p0 / 42;
    int oy_hi = (p0 + 63) / 42; if (oy_hi > 41) oy_hi = 41;
    int y_lo = 2 * oy_lo - 1;
    int rows = 2 * oy_hi + 2 - y_lo;   // <= 7

    if (tid < 256) ((uint4*)wBs)[tid] = ((const uint4*)wB1g)[tid];
    const float* inb = in + (size_t)n * 4 * 7056;
    for (int i = tid; i < rows * 336; i += 256) {
        int r = i / 336, rem = i % 336, ci = rem / 84, x = rem % 84;
        int y = y_lo + r;
        float v = (y >= 0) ? inb[ci * 7056 + y * 84 + x] : 0.0f;
        ins[(r * 84 + x) * 4 + ci] = f2bf(v);
    }
    __syncthreads();
    // zero K-pad region [36,72)
    for (int i = tid; i < 576; i += 256) {
        int m = i / 9, q = i % 9;
        uint2 z; z.x = 0u; z.y = 0u;
        *(uint2*)&A[m * 72 + 36 + q * 4] = z;
    }
    // im2col fill k in [0,36)
    for (int i = tid; i < 576; i += 256) {
        int m = i / 9, kk = i % 9;
        int kh = kk / 3, kw = kk - kh * 3;
        int p = p0 + m;
        uint2 v; v.x = 0u; v.y = 0u;
        if (p < 1764) {
            int oy = p / 42, ox = p - oy * 42;
            int y = 2 * oy - 1 + kh, x = 2 * ox - 1 + kw;
            if ((unsigned)y < 84u && (unsigned)x < 84u)
                v = *(const uint2*)&ins[((y - y_lo) * 84 + x) * 4];
        }
        *(uint2*)&A[m * 72 + kk * 4] = v;
    }
    __syncthreads();
    int lane = tid & 63, g = tid >> 6, quad = lane >> 4, c16 = lane & 15;
    int ma = g * 16 + c16;
    short8 a0 = *(const short8*)&A[ma * 72 + quad * 8];
    short8 a1 = *(const short8*)&A[ma * 72 + 32 + quad * 8];
    #pragma unroll
    for (int nt = 0; nt < 2; nt++) {
        float bv = b1[nt * 16 + c16];
        f32x4 acc = {bv, bv, bv, bv};
        short8 b0 = *(const short8*)&wBs[((nt * 2 + 0) * 64 + lane) * 8];
        short8 bq = *(const short8*)&wBs[((nt * 2 + 1) * 64 + lane) * 8];
        acc = MFMA(a0, b0, acc);
        acc = MFMA(a1, bq, acc);
        #pragma unroll
        for (int r = 0; r < 4; r++) {
            int p = p0 + g * 16 + 4 * quad + r;
            if (p < 1764) {
                float v = acc[r];
                v = v > 0.0f ? v : expm1f(v);
                x1[((size_t)nl * 1764 + p) * 32 + nt * 16 + c16] = f2bf(v);
            }
        }
    }
}

// ============================================================================
// convN (conv2/3/4): channel-last bf16 in, 3x3 s2 p1, Cin=Cout=32, K=288.
// im2col in LDS (row pad +8 -> 2-way max bank alias), 9-chunk MFMA.
// OUTMODE 0: [n][HO][WO][32]; OUTMODE 1: NCHW-flat [n][co*36+p] (conv4).
// ============================================================================
template<int HI, int HO, int OUTMODE>
__global__ __launch_bounds__(256) void convN_kernel(
    const bf16* __restrict__ xin, bf16* __restrict__ xout,
    const bf16* __restrict__ wBg, const float* __restrict__ bias, int n0)
{
    constexpr int NPIX = HO * HO;
    constexpr int NBLK = (NPIX + 63) / 64;
    __shared__ bf16 A[64 * 296];       // 37,888 B
    __shared__ bf16 wBs[9216];         // 18,432 B
    int tid = threadIdx.x;
    int nl = blockIdx.x / NBLK, blk = blockIdx.x % NBLK;
    int p0 = blk * 64;
    for (int i = tid; i < 1152; i += 256) ((uint4*)wBs)[i] = ((const uint4*)wBg)[i];
    const bf16* xb = xin + (size_t)nl * HI * HI * 32;
    for (int i = tid; i < 2304; i += 256) {
        int m = i / 36, t = i % 36, kk = t >> 2, part = t & 3;
        int kh = kk / 3, kw = kk - kh * 3;
        int p = p0 + m;
        uint4 v; v.x = v.y = v.z = v.w = 0u;
        if (p < NPIX) {
            int oy = p / HO, ox = p - oy * HO;
            int y = 2 * oy - 1 + kh, x = 2 * ox - 1 + kw;
            if ((unsigned)y < (unsigned)HI && (unsigned)x < (unsigned)HI)
                v = *(const uint4*)&xb[((size_t)(y * HI + x)) * 32 + part * 8];
        }
        *(uint4*)&A[m * 296 + kk * 32 + part * 8] = v;
    }
    __syncthreads();
    int lane = tid & 63, g = tid >> 6, quad = lane >> 4, c16 = lane & 15;
    int ma = g * 16 + c16;
    short8 af[9];
    #pragma unroll
    for (int kk = 0; kk < 9; kk++)
        af[kk] = *(const short8*)&A[ma * 296 + kk * 32 + quad * 8];
    #pragma unroll
    for (int nt = 0; nt < 2; nt++) {
        float bv = bias[nt * 16 + c16];
        f32x4 acc = {bv, bv, bv, bv};
        #pragma unroll
        for (int kk = 0; kk < 9; kk++) {
            short8 bfr = *(const short8*)&wBs[((nt * 9 + kk) * 64 + lane) * 8];
            acc = MFMA(af[kk], bfr, acc);
        }
        #pragma unroll
        for (int r = 0; r < 4; r++) {
            int p = p0 + g * 16 + 4 * quad + r;
            if (p < NPIX) {
                float v = acc[r];
                v = v > 0.0f ? v : expm1f(v);
                if (OUTMODE == 0)
                    xout[(((size_t)(n0 + nl)) * NPIX + p) * 32 + nt * 16 + c16] = f2bf(v);
                else
                    xout[(size_t)(n0 + nl) * FEAT + (nt * 16 + c16) * 36 + p] = f2bf(v);
            }
        }
    }
}

// ============================================================================
// GI = x4 @ W_ih^T + biasg : [2048,1152]bf16 x [1152,768] -> f32. MFMA.
// B-frags direct from global (frag-ordered, L2-resident 1.8MB).
// ============================================================================
__global__ __launch_bounds__(256) void gemm_gi_kernel(
    const bf16* __restrict__ X, const bf16* __restrict__ wihF,
    const float* __restrict__ biasg, float* __restrict__ GI)
{
    __shared__ bf16 As[64 * 40];
    int tid = threadIdx.x;
    int m0 = blockIdx.x * 64, nb = blockIdx.y * 4, n0 = blockIdx.y * 64;
    int lane = tid & 63, g = tid >> 6, quad = lane >> 4, c16 = lane & 15;
    f32x4 acc[4];
    #pragma unroll
    for (int st = 0; st < 4; st++) {
        float bv = biasg[n0 + st * 16 + c16];
        acc[st] = (f32x4){bv, bv, bv, bv};
    }
    int sm = tid >> 2, sp = tid & 3;
    for (int ch = 0; ch < 36; ch++) {
        __syncthreads();
        *(uint4*)&As[sm * 40 + sp * 8] =
            *(const uint4*)&X[(size_t)(m0 + sm) * FEAT + ch * 32 + sp * 8];
        __syncthreads();
        short8 af = *(const short8*)&As[(g * 16 + c16) * 40 + quad * 8];
        #pragma unroll
        for (int st = 0; st < 4; st++) {
            short8 bfr = *(const short8*)&wihF[(((size_t)ch * 48 + nb + st) * 64 + lane) * 8];
            acc[st] = MFMA(af, bfr, acc[st]);
        }
    }
    #pragma unroll
    for (int st = 0; st < 4; st++)
        #pragma unroll
        for (int r = 0; r < 4; r++)
            GI[(size_t)(m0 + g * 16 + 4 * quad + r) * G3 + n0 + st * 16 + c16] = acc[st][r];
}

// ---------------- GRU scan: one block per batch row, bf16 W_hh ----------------
__global__ __launch_bounds__(256) void scan_kernel(
    const float* __restrict__ GI, const bf16* __restrict__ whhB,
    const float* __restrict__ b_hh, const float* __restrict__ rnn_in,
    const float* __restrict__ mask, float* __restrict__ H)
{
    __shared__ float hs[HID];
    int b = blockIdx.x, j = threadIdx.x;
    float h = rnn_in[b * HID + j];
    float bhn = b_hh[2 * HID + j];
    for (int t = 0; t < TT; t++) {
        float m = mask[t * BB + b];
        h *= m;
        hs[j] = h;
        __syncthreads();
        float ar = 0.f, az = 0.f, an = 0.f;
        #pragma unroll 4
        for (int k = 0; k < HID; k++) {
            float hk = hs[k];
            const bf16* wp = whhB + (size_t)k * G3 + j;
            ar += hk * bf2f(wp[0]);
            az += hk * bf2f(wp[256]);
            an += hk * bf2f(wp[512]);
        }
        int row = t * BB + b;
        const float* gp = GI + (size_t)row * G3 + j;
        float r = 1.0f / (1.0f + expf(-(gp[0] + ar)));
        float z = 1.0f / (1.0f + expf(-(gp[256] + az)));
        float pre = gp[512] + r * (an + bhn);
        pre = fminf(15.0f, fmaxf(-15.0f, pre));
        float e = expf(2.0f * pre);
        float nn = (e - 1.0f) / (e + 1.0f);
        h = (1.0f - z) * nn + z * h;
        H[(size_t)row * HID + j] = h;
        __syncthreads();
    }
}

// ---------------- heads: v, actions, logp_a, ent (float32 out) ----------------
__global__ __launch_bounds__(256) void heads_kernel(
    const float* __restrict__ H, const int* __restrict__ actions,
    const float* __restrict__ Wc, const float* __restrict__ bc,
    const float* __restrict__ Wa, const float* __restrict__ ba,
    float* __restrict__ out)
{
    int r = blockIdx.x * 256 + threadIdx.x;
    if (r >= NB) return;
    const float* h = H + (size_t)r * HID;
    float v = bc[0];
    for (int k = 0; k < HID; k++) v += h[k] * Wc[k];
    float lg[NA];
    for (int a = 0; a < NA; a++) {
        float s = ba[a];
        const float* wa = Wa + a * HID;
        for (int k = 0; k < HID; k++) s += h[k] * wa[k];
        lg[a] = s;
    }
    float mx = lg[0];
    for (int a = 1; a < NA; a++) mx = fmaxf(mx, lg[a]);
    float Z = 0.f;
    for (int a = 0; a < NA; a++) Z += expf(lg[a] - mx);
    float lse = mx + logf(Z);
    int act = actions[r];
    float logp_a = lg[act] - lse;
    float ent = 0.f;
    for (int a = 0; a < NA; a++) {
        float lp = lg[a] - lse;
        ent -= expf(lp) * lp;
    }
    out[r]          = v;
    out[NB + r]     = (float)act;
    out[2 * NB + r] = logp_a;
    out[3 * NB + r] = ent;
}

__global__ __launch_bounds__(256) void hfin_kernel(const float* __restrict__ H, float* __restrict__ out)
{
    int i = blockIdx.x * 256 + threadIdx.x;
    if (i < BB * HID)
        out[4 * NB + i] = H[(size_t)(TT - 1) * BB * HID + i];
}

extern "C" void kernel_launch(void* const* d_in, const int* in_sizes, int n_in,
                              void* d_out, int out_size, void* d_ws, size_t ws_size,
                              hipStream_t stream) {
    const float* inputs  = (const float*)d_in[0];
    const float* rnn_in  = (const float*)d_in[1];
    const float* mask    = (const float*)d_in[2];
    const int*   actions = (const int*)d_in[3];
    const float* w1 = (const float*)d_in[4];
    const float* b1 = (const float*)d_in[5];
    const float* w2 = (const float*)d_in[6];
    const float* b2 = (const float*)d_in[7];
    const float* w3 = (const float*)d_in[8];
    const float* b3 = (const float*)d_in[9];
    const float* w4 = (const float*)d_in[10];
    const float* b4 = (const float*)d_in[11];
    const float* W_ih = (const float*)d_in[12];
    const float* W_hh = (const float*)d_in[13];
    const float* b_ih = (const float*)d_in[14];
    const float* b_hh = (const float*)d_in[15];
    const float* Wc = (const float*)d_in[16];
    const float* bc = (const float*)d_in[17];
    const float* Wa = (const float*)d_in[18];
    const float* ba = (const float*)d_in[19];
    float* out = (float*)d_out;

    // workspace layout (~93.7 MB, overlaid regions)
    char* ws = (char*)d_ws;
    size_t o = 0;
    auto nxt = [&](size_t b) { void* p = ws + o; o += (b + 255) & ~(size_t)255; return p; };
    bf16* wB1  = (bf16*)nxt(2048 * 2);
    bf16* wB2  = (bf16*)nxt(9216 * 2);
    bf16* wB3  = (bf16*)nxt(9216 * 2);
    bf16* wB4  = (bf16*)nxt(9216 * 2);
    bf16* wihF = (bf16*)nxt(884736 * 2);
    bf16* whhB = (bf16*)nxt(196608 * 2);
    float* biasg = (float*)nxt(768 * 4);
    bf16* x4 = (bf16*)nxt((size_t)NB * FEAT * 2);            //  4.72 MB
    bf16* x2 = (bf16*)nxt((size_t)NB * 441 * 32 * 2);        // 57.80 MB
    char* R1 = (char*)nxt(28901376);                          // 28.90 MB shared region
    bf16*  x1c = (bf16*)R1;                                   // conv1/conv2 chunk scratch
    bf16*  x3  = (bf16*)R1;                                   // after conv2 done (15.86 MB)
    float* GI  = (float*)(R1 + 15859712);                     // 6.29 MB
    float* H   = (float*)(R1 + 15859712 + 6291456);           // 2.10 MB

    prep_kernel<<<3456, 256, 0, stream>>>(w1, w2, w3, w4, W_ih, W_hh, b_ih, b_hh,
                                          wB1, wB2, wB3, wB4, wihF, whhB, biasg);
    // conv1+conv2 in 8 image-chunks of 256 (x1 chunk scratch = 28.9 MB)
    for (int c = 0; c < 8; c++) {
        conv1_kernel<<<256 * 28, 256, 0, stream>>>(inputs, c * 256, wB1, b1, x1c);
        convN_kernel<42, 21, 0><<<256 * 7, 256, 0, stream>>>(x1c, x2, wB2, b2, c * 256);
    }
    convN_kernel<21, 11, 0><<<2048 * 2, 256, 0, stream>>>(x2, x3, wB3, b3, 0);
    convN_kernel<11, 6, 1><<<2048, 256, 0, stream>>>(x3, x4, wB4, b4, 0);
    gemm_gi_kernel<<<dim3(32, 12), 256, 0, stream>>>(x4, wihF, biasg, GI);
    scan_kernel<<<BB, HID, 0, stream>>>(GI, whhB, b_hh, rnn_in, mask, H);
    heads_kernel<<<NB / 256, 256, 0, stream>>>(H, actions, Wc, bc, Wa, ba, out);
    hfin_kernel<<<(BB * HID + 255) / 256, 256, 0, stream>>>(H, out);
}

// Round 4
// 1705.058 us; speedup vs baseline: 2.8695x; 1.0686x over previous
//
#include <hip/hip_runtime.h>
#include <hip/hip_bf16.h>
#include <math.h>

#define TT 64
#define BB 32
#define HID 256
#define NA 12
#define FEAT 1152
#define NB 2048           // T*B
#define G3 768            // 3*HID

typedef __hip_bfloat16 bf16;
typedef __attribute__((ext_vector_type(8))) short short8;
typedef __attribute__((ext_vector_type(4))) float f32x4;

static __device__ __forceinline__ float bf2f(bf16 v) { return __bfloat162float(v); }
static __device__ __forceinline__ bf16 f2bf(float v) { return __float2bfloat16(v); }

#define MFMA(a, b, c) __builtin_amdgcn_mfma_f32_16x16x32_bf16((a), (b), (c), 0, 0, 0)

// ============================================================================
// prep: build fragment-ordered bf16 weights once.
//   A: lane l holds A[m=l&15][k=8*(l>>4)+j]
//   B: lane l holds B[k=8*(l>>4)+j][n=l&15]
//   D: lane l reg r holds D[row=4*(l>>4)+r][col=l&15]
// whh16: straight bf16 copy of W_hh [768][256] row-major (for VGPR-resident scan)
// ============================================================================
__global__ __launch_bounds__(256) void prep_kernel(
    const float* __restrict__ w1, const float* __restrict__ w2,
    const float* __restrict__ w3, const float* __restrict__ w4,
    const float* __restrict__ W_ih, const float* __restrict__ W_hh,
    const float* __restrict__ b_ih, const float* __restrict__ b_hh,
    bf16* __restrict__ wB1, bf16* __restrict__ wB2,
    bf16* __restrict__ wB3, bf16* __restrict__ wB4,
    bf16* __restrict__ wihF, bf16* __restrict__ whh16, float* __restrict__ biasg)
{
    int i = blockIdx.x * 256 + threadIdx.x;
    if (i < 2048) {              // wB1[nt][ch][lane][j], K=36 padded to 64
        int j = i & 7, l = (i >> 3) & 63, rest = i >> 9;
        int ch = rest & 1, nt = rest >> 1;
        int k = ch * 32 + 8 * (l >> 4) + j;          // k = kk*4 + ci
        int co = nt * 16 + (l & 15);
        wB1[i] = f2bf(k < 36 ? w1[co * 36 + (k & 3) * 9 + (k >> 2)] : 0.0f);
    }
    if (i < 9216) {              // wB2/3/4[nt][kk][lane][j], k = kk*32 + ci
        int j = i & 7, l = (i >> 3) & 63, rest = i >> 9;
        int kk = rest % 9, nt = rest / 9;
        int ci = 8 * (l >> 4) + j, co = nt * 16 + (l & 15);
        wB2[i] = f2bf(w2[co * 288 + ci * 9 + kk]);
        wB3[i] = f2bf(w3[co * 288 + ci * 9 + kk]);
        wB4[i] = f2bf(w4[co * 288 + ci * 9 + kk]);
    }
    if (i < 884736) {            // wihF[ch(36)][st(48)][lane][j]
        int j = i & 7, l = (i >> 3) & 63, rest = i >> 9;
        int st = rest % 48, ch = rest / 48;
        int k = ch * 32 + 8 * (l >> 4) + j, n = st * 16 + (l & 15);
        wihF[i] = f2bf(W_ih[(size_t)n * FEAT + k]);
    }
    if (i < 196608) {            // whh16 flat bf16 copy, [g][k] row-major
        whh16[i] = f2bf(W_hh[i]);
    }
    if (i < G3) biasg[i] = b_ih[i] + (i < 2 * HID ? b_hh[i] : 0.0f);
}

// ============================================================================
// conv1: [CH,4,84,84] f32 -> x1 [CH,42,42,32] bf16 channel-last. K=36 pad 64.
// ============================================================================
__global__ __launch_bounds__(256) void conv1_kernel(
    const float* __restrict__ in, int n0,
    const bf16* __restrict__ wB1g, const float* __restrict__ b1,
    bf16* __restrict__ x1)
{
    __shared__ bf16 ins[7 * 84 * 4];   // [r][x][ci]
    __shared__ bf16 A[64 * 72];        // KP1 = 72 (64 + 8 pad)
    __shared__ bf16 wBs[2048];
    int tid = threadIdx.x;
    int nl = blockIdx.x / 28, blk = blockIdx.x % 28;
    int n = n0 + nl;
    int p0 = blk * 64;
    int oy_lo = p0 / 42;
    int oy_hi = (p0 + 63) / 42; if (oy_hi > 41) oy_hi = 41;
    int y_lo = 2 * oy_lo - 1;
    int rows = 2 * oy_hi + 2 - y_lo;   // <= 7

    if (tid < 256) ((uint4*)wBs)[tid] = ((const uint4*)wB1g)[tid];
    const float* inb = in + (size_t)n * 4 * 7056;
    for (int i = tid; i < rows * 336; i += 256) {
        int r = i / 336, rem = i % 336, ci = rem / 84, x = rem % 84;
        int y = y_lo + r;
        float v = (y >= 0) ? inb[ci * 7056 + y * 84 + x] : 0.0f;
        ins[(r * 84 + x) * 4 + ci] = f2bf(v);
    }
    __syncthreads();
    for (int i = tid; i < 576; i += 256) {
        int m = i / 9, q = i % 9;
        uint2 z; z.x = 0u; z.y = 0u;
        *(uint2*)&A[m * 72 + 36 + q * 4] = z;
    }
    for (int i = tid; i < 576; i += 256) {
        int m = i / 9, kk = i % 9;
        int kh = kk / 3, kw = kk - kh * 3;
        int p = p0 + m;
        uint2 v; v.x = 0u; v.y = 0u;
        if (p < 1764) {
            int oy = p / 42, ox = p - oy * 42;
            int y = 2 * oy - 1 + kh, x = 2 * ox - 1 + kw;
            if ((unsigned)y < 84u && (unsigned)x < 84u)
                v = *(const uint2*)&ins[((y - y_lo) * 84 + x) * 4];
        }
        *(uint2*)&A[m * 72 + kk * 4] = v;
    }
    __syncthreads();
    int lane = tid & 63, g = tid >> 6, quad = lane >> 4, c16 = lane & 15;
    int ma = g * 16 + c16;
    short8 a0 = *(const short8*)&A[ma * 72 + quad * 8];
    short8 a1 = *(const short8*)&A[ma * 72 + 32 + quad * 8];
    #pragma unroll
    for (int nt = 0; nt < 2; nt++) {
        float bv = b1[nt * 16 + c16];
        f32x4 acc = {bv, bv, bv, bv};
        short8 b0 = *(const short8*)&wBs[((nt * 2 + 0) * 64 + lane) * 8];
        short8 bq = *(const short8*)&wBs[((nt * 2 + 1) * 64 + lane) * 8];
        acc = MFMA(a0, b0, acc);
        acc = MFMA(a1, bq, acc);
        #pragma unroll
        for (int r = 0; r < 4; r++) {
            int p = p0 + g * 16 + 4 * quad + r;
            if (p < 1764) {
                float v = acc[r];
                v = v > 0.0f ? v : expm1f(v);
                x1[((size_t)nl * 1764 + p) * 32 + nt * 16 + c16] = f2bf(v);
            }
        }
    }
}

// ============================================================================
// convN (conv2/3/4): channel-last bf16 in, 3x3 s2 p1, Cin=Cout=32, K=288.
// ============================================================================
template<int HI, int HO, int OUTMODE>
__global__ __launch_bounds__(256) void convN_kernel(
    const bf16* __restrict__ xin, bf16* __restrict__ xout,
    const bf16* __restrict__ wBg, const float* __restrict__ bias, int n0)
{
    constexpr int NPIX = HO * HO;
    constexpr int NBLK = (NPIX + 63) / 64;
    __shared__ bf16 A[64 * 296];       // 37,888 B
    __shared__ bf16 wBs[9216];         // 18,432 B
    int tid = threadIdx.x;
    int nl = blockIdx.x / NBLK, blk = blockIdx.x % NBLK;
    int p0 = blk * 64;
    for (int i = tid; i < 1152; i += 256) ((uint4*)wBs)[i] = ((const uint4*)wBg)[i];
    const bf16* xb = xin + (size_t)nl * HI * HI * 32;
    for (int i = tid; i < 2304; i += 256) {
        int m = i / 36, t = i % 36, kk = t >> 2, part = t & 3;
        int kh = kk / 3, kw = kk - kh * 3;
        int p = p0 + m;
        uint4 v; v.x = v.y = v.z = v.w = 0u;
        if (p < NPIX) {
            int oy = p / HO, ox = p - oy * HO;
            int y = 2 * oy - 1 + kh, x = 2 * ox - 1 + kw;
            if ((unsigned)y < (unsigned)HI && (unsigned)x < (unsigned)HI)
                v = *(const uint4*)&xb[((size_t)(y * HI + x)) * 32 + part * 8];
        }
        *(uint4*)&A[m * 296 + kk * 32 + part * 8] = v;
    }
    __syncthreads();
    int lane = tid & 63, g = tid >> 6, quad = lane >> 4, c16 = lane & 15;
    int ma = g * 16 + c16;
    short8 af[9];
    #pragma unroll
    for (int kk = 0; kk < 9; kk++)
        af[kk] = *(const short8*)&A[ma * 296 + kk * 32 + quad * 8];
    #pragma unroll
    for (int nt = 0; nt < 2; nt++) {
        float bv = bias[nt * 16 + c16];
        f32x4 acc = {bv, bv, bv, bv};
        #pragma unroll
        for (int kk = 0; kk < 9; kk++) {
            short8 bfr = *(const short8*)&wBs[((nt * 9 + kk) * 64 + lane) * 8];
            acc = MFMA(af[kk], bfr, acc);
        }
        #pragma unroll
        for (int r = 0; r < 4; r++) {
            int p = p0 + g * 16 + 4 * quad + r;
            if (p < NPIX) {
                float v = acc[r];
                v = v > 0.0f ? v : expm1f(v);
                if (OUTMODE == 0)
                    xout[(((size_t)(n0 + nl)) * NPIX + p) * 32 + nt * 16 + c16] = f2bf(v);
                else
                    xout[(size_t)(n0 + nl) * FEAT + (nt * 16 + c16) * 36 + p] = f2bf(v);
            }
        }
    }
}

// ============================================================================
// GI = x4 @ W_ih^T + biasg : [2048,1152]bf16 x [1152,768] -> f32. MFMA.
// ============================================================================
__global__ __launch_bounds__(256) void gemm_gi_kernel(
    const bf16* __restrict__ X, const bf16* __restrict__ wihF,
    const float* __restrict__ biasg, float* __restrict__ GI)
{
    __shared__ bf16 As[64 * 40];
    int tid = threadIdx.x;
    int m0 = blockIdx.x * 64, nb = blockIdx.y * 4, n0 = blockIdx.y * 64;
    int lane = tid & 63, g = tid >> 6, quad = lane >> 4, c16 = lane & 15;
    f32x4 acc[4];
    #pragma unroll
    for (int st = 0; st < 4; st++) {
        float bv = biasg[n0 + st * 16 + c16];
        acc[st] = (f32x4){bv, bv, bv, bv};
    }
    int sm = tid >> 2, sp = tid & 3;
    for (int ch = 0; ch < 36; ch++) {
        __syncthreads();
        *(uint4*)&As[sm * 40 + sp * 8] =
            *(const uint4*)&X[(size_t)(m0 + sm) * FEAT + ch * 32 + sp * 8];
        __syncthreads();
        short8 af = *(const short8*)&As[(g * 16 + c16) * 40 + quad * 8];
        #pragma unroll
        for (int st = 0; st < 4; st++) {
            short8 bfr = *(const short8*)&wihF[(((size_t)ch * 48 + nb + st) * 64 + lane) * 8];
            acc[st] = MFMA(af, bfr, acc[st]);
        }
    }
    #pragma unroll
    for (int st = 0; st < 4; st++)
        #pragma unroll
        for (int r = 0; r < 4; r++)
            GI[(size_t)(m0 + g * 16 + 4 * quad + r) * G3 + n0 + st * 16 + c16] = acc[st][r];
}

// ============================================================================
// GRU scan: 32 blocks (one per batch row) x 768 threads (one per gate-column).
// W_hh row (256 bf16 = 512B) VGPR-resident: 32 x uint4 = 128 VGPRs/thread.
// Step loop: 64 broadcast ds_read_b128 + 512 VALU per thread, zero weight loads.
// ============================================================================
__global__ __launch_bounds__(768, 3) void scan_kernel(
    const float* __restrict__ GI, const bf16* __restrict__ whh16,
    const float* __restrict__ b_hh, const float* __restrict__ rnn_in,
    const float* __restrict__ mask, float* __restrict__ H)
{
    __shared__ float hs[HID];
    __shared__ float pr[HID];
    __shared__ float pz[HID];
    __shared__ float pn[HID];
    int b = blockIdx.x, t = threadIdx.x;
    int gate = t >> 8, j = t & 255;

    uint4 wreg[32];
    const uint4* wrow = (const uint4*)(whh16 + (size_t)t * HID);
    #pragma unroll
    for (int kc = 0; kc < 32; kc++) wreg[kc] = wrow[kc];

    float bhn = (gate == 2) ? b_hh[2 * HID + j] : 0.0f;
    if (t < HID) hs[t] = rnn_in[b * HID + t] * mask[b];
    __syncthreads();

    for (int step = 0; step < TT; step++) {
        int row = step * BB + b;
        // combiner-thread prefetches (issued before the dot, consumed after barrier)
        float gr = 0.f, gz = 0.f, gn = 0.f, hold = 0.f, mnext = 1.0f;
        if (gate == 0) {
            const float* gp = GI + (size_t)row * G3 + j;
            gr = gp[0]; gz = gp[256]; gn = gp[512];
            hold = hs[j];
            if (step + 1 < TT) mnext = mask[(step + 1) * BB + b];
        }
        float acc = bhn;
        #pragma unroll
        for (int kc = 0; kc < 32; kc++) {
            uint4 w = wreg[kc];
            float4 h0 = *(const float4*)&hs[kc * 8];
            float4 h1 = *(const float4*)&hs[kc * 8 + 4];
            acc = fmaf(h0.x, __uint_as_float(w.x << 16), acc);
            acc = fmaf(h0.y, __uint_as_float(w.x & 0xffff0000u), acc);
            acc = fmaf(h0.z, __uint_as_float(w.y << 16), acc);
            acc = fmaf(h0.w, __uint_as_float(w.y & 0xffff0000u), acc);
            acc = fmaf(h1.x, __uint_as_float(w.z << 16), acc);
            acc = fmaf(h1.y, __uint_as_float(w.z & 0xffff0000u), acc);
            acc = fmaf(h1.z, __uint_as_float(w.w << 16), acc);
            acc = fmaf(h1.w, __uint_as_float(w.w & 0xffff0000u), acc);
        }
        if (gate == 0)      pr[j] = acc;
        else if (gate == 1) pz[j] = acc;
        else                pn[j] = acc;
        __syncthreads();
        if (gate == 0) {
            float r = 1.0f / (1.0f + expf(-(gr + pr[j])));
            float z = 1.0f / (1.0f + expf(-(gz + pz[j])));
            float pre = gn + r * pn[j];
            pre = fminf(15.0f, fmaxf(-15.0f, pre));
            float e = expf(2.0f * pre);
            float nn = (e - 1.0f) / (e + 1.0f);
            float hnew = (1.0f - z) * nn + z * hold;
            H[(size_t)row * HID + j] = hnew;
            hs[j] = hnew * mnext;
        }
        __syncthreads();
    }
}

// ---------------- heads: v, actions, logp_a, ent (float32 out) ----------------
__global__ __launch_bounds__(256) void heads_kernel(
    const float* __restrict__ H, const int* __restrict__ actions,
    const float* __restrict__ Wc, const float* __restrict__ bc,
    const float* __restrict__ Wa, const float* __restrict__ ba,
    float* __restrict__ out)
{
    int r = blockIdx.x * 256 + threadIdx.x;
    if (r >= NB) return;
    const float* h = H + (size_t)r * HID;
    float v = bc[0];
    for (int k = 0; k < HID; k++) v += h[k] * Wc[k];
    float lg[NA];
    for (int a = 0; a < NA; a++) {
        float s = ba[a];
        const float* wa = Wa + a * HID;
        for (int k = 0; k < HID; k++) s += h[k] * wa[k];
        lg[a] = s;
    }
    float mx = lg[0];
    for (int a = 1; a < NA; a++) mx = fmaxf(mx, lg[a]);
    float Z = 0.f;
    for (int a = 0; a < NA; a++) Z += expf(lg[a] - mx);
    float lse = mx + logf(Z);
    int act = actions[r];
    float logp_a = lg[act] - lse;
    float ent = 0.f;
    for (int a = 0; a < NA; a++) {
        float lp = lg[a] - lse;
        ent -= expf(lp) * lp;
    }
    out[r]          = v;
    out[NB + r]     = (float)act;
    out[2 * NB + r] = logp_a;
    out[3 * NB + r] = ent;
}

__global__ __launch_bounds__(256) void hfin_kernel(const float* __restrict__ H, float* __restrict__ out)
{
    int i = blockIdx.x * 256 + threadIdx.x;
    if (i < BB * HID)
        out[4 * NB + i] = H[(size_t)(TT - 1) * BB * HID + i];
}

extern "C" void kernel_launch(void* const* d_in, const int* in_sizes, int n_in,
                              void* d_out, int out_size, void* d_ws, size_t ws_size,
                              hipStream_t stream) {
    const float* inputs  = (const float*)d_in[0];
    const float* rnn_in  = (const float*)d_in[1];
    const float* mask    = (const float*)d_in[2];
    const int*   actions = (const int*)d_in[3];
    const float* w1 = (const float*)d_in[4];
    const float* b1 = (const float*)d_in[5];
    const float* w2 = (const float*)d_in[6];
    const float* b2 = (const float*)d_in[7];
    const float* w3 = (const float*)d_in[8];
    const float* b3 = (const float*)d_in[9];
    const float* w4 = (const float*)d_in[10];
    const float* b4 = (const float*)d_in[11];
    const float* W_ih = (const float*)d_in[12];
    const float* W_hh = (const float*)d_in[13];
    const float* b_ih = (const float*)d_in[14];
    const float* b_hh = (const float*)d_in[15];
    const float* Wc = (const float*)d_in[16];
    const float* bc = (const float*)d_in[17];
    const float* Wa = (const float*)d_in[18];
    const float* ba = (const float*)d_in[19];
    float* out = (float*)d_out;

    char* ws = (char*)d_ws;
    size_t o = 0;
    auto nxt = [&](size_t b) { void* p = ws + o; o += (b + 255) & ~(size_t)255; return p; };
    bf16* wB1  = (bf16*)nxt(2048 * 2);
    bf16* wB2  = (bf16*)nxt(9216 * 2);
    bf16* wB3  = (bf16*)nxt(9216 * 2);
    bf16* wB4  = (bf16*)nxt(9216 * 2);
    bf16* wihF = (bf16*)nxt(884736 * 2);
    bf16* whh16 = (bf16*)nxt(196608 * 2);
    float* biasg = (float*)nxt(768 * 4);
    bf16* x4 = (bf16*)nxt((size_t)NB * FEAT * 2);            //  4.72 MB
    bf16* x2 = (bf16*)nxt((size_t)NB * 441 * 32 * 2);        // 57.80 MB

    // dynamic conv1/conv2 chunking based on available workspace
    const size_t X1_PER_IMG = 1764 * 32 * 2;                  // 112,896 B
    const size_t TAILFIX = 15859712 + 6291456 + 2097152 + 1024; // x3+GI+H
    bf16* x3; float* GI; float* H; bf16* x1c;
    int CH;
    if (ws_size >= o + TAILFIX + 2048 * X1_PER_IMG + (1u << 20)) {
        CH = 2048;
        x3 = (bf16*)nxt(15859712); GI = (float*)nxt(6291456); H = (float*)nxt(2097152);
        x1c = (bf16*)nxt(2048 * X1_PER_IMG);
    } else if (ws_size >= o + TAILFIX + 512 * X1_PER_IMG + (1u << 20)) {
        CH = 512;
        x3 = (bf16*)nxt(15859712); GI = (float*)nxt(6291456); H = (float*)nxt(2097152);
        x1c = (bf16*)nxt(512 * X1_PER_IMG);
    } else if (ws_size >= o + TAILFIX + 256 * X1_PER_IMG + (1u << 20)) {
        CH = 256;
        x3 = (bf16*)nxt(15859712); GI = (float*)nxt(6291456); H = (float*)nxt(2097152);
        x1c = (bf16*)nxt(256 * X1_PER_IMG);
    } else {
        // known-good overlay layout (93.7 MB total): x1c shares region with x3/GI/H
        CH = 256;
        char* R1 = (char*)nxt(28901376);
        x1c = (bf16*)R1;
        x3  = (bf16*)R1;
        GI  = (float*)(R1 + 15859712);
        H   = (float*)(R1 + 15859712 + 6291456);
    }

    prep_kernel<<<3456, 256, 0, stream>>>(w1, w2, w3, w4, W_ih, W_hh, b_ih, b_hh,
                                          wB1, wB2, wB3, wB4, wihF, whh16, biasg);
    for (int c = 0; c < 2048 / CH; c++) {
        conv1_kernel<<<CH * 28, 256, 0, stream>>>(inputs, c * CH, wB1, b1, x1c);
        convN_kernel<42, 21, 0><<<CH * 7, 256, 0, stream>>>(x1c, x2, wB2, b2, c * CH);
    }
    convN_kernel<21, 11, 0><<<2048 * 2, 256, 0, stream>>>(x2, x3, wB3, b3, 0);
    convN_kernel<11, 6, 1><<<2048, 256, 0, stream>>>(x3, x4, wB4, b4, 0);
    gemm_gi_kernel<<<dim3(32, 12), 256, 0, stream>>>(x4, wihF, biasg, GI);
    scan_kernel<<<BB, 768, 0, stream>>>(GI, whh16, b_hh, rnn_in, mask, H);
    heads_kernel<<<NB / 256, 256, 0, stream>>>(H, actions, Wc, bc, Wa, ba, out);
    hfin_kernel<<<(BB * HID + 255) / 256, 256, 0, stream>>>(H, out);
}

// Round 5
// 1641.245 us; speedup vs baseline: 2.9811x; 1.0389x over previous
//
#include <hip/hip_runtime.h>
#include <hip/hip_bf16.h>
#include <math.h>

#define TT 64
#define BB 32
#define HID 256
#define NA 12
#define FEAT 1152
#define NB 2048           // T*B
#define G3 768            // 3*HID

typedef __hip_bfloat16 bf16;
typedef __attribute__((ext_vector_type(8))) short short8;
typedef __attribute__((ext_vector_type(4))) float f32x4;

static __device__ __forceinline__ float bf2f(bf16 v) { return __bfloat162float(v); }
static __device__ __forceinline__ bf16 f2bf(float v) { return __float2bfloat16(v); }

#define MFMA(a, b, c) __builtin_amdgcn_mfma_f32_16x16x32_bf16((a), (b), (c), 0, 0, 0)

// ============================================================================
// prep: build fragment-ordered bf16 weights once.
//   A: lane l holds A[m=l&15][k=8*(l>>4)+j]
//   B: lane l holds B[k=8*(l>>4)+j][n=l&15]
//   D: lane l reg r holds D[row=4*(l>>4)+r][col=l&15]
// whh16: straight bf16 copy of W_hh [768][256] row-major (for VGPR-resident scan)
// ============================================================================
__global__ __launch_bounds__(256) void prep_kernel(
    const float* __restrict__ w1, const float* __restrict__ w2,
    const float* __restrict__ w3, const float* __restrict__ w4,
    const float* __restrict__ W_ih, const float* __restrict__ W_hh,
    const float* __restrict__ b_ih, const float* __restrict__ b_hh,
    bf16* __restrict__ wB1, bf16* __restrict__ wB2,
    bf16* __restrict__ wB3, bf16* __restrict__ wB4,
    bf16* __restrict__ wihF, bf16* __restrict__ whh16, float* __restrict__ biasg)
{
    int i = blockIdx.x * 256 + threadIdx.x;
    if (i < 2048) {              // wB1[nt][ch][lane][j], K=36 padded to 64
        int j = i & 7, l = (i >> 3) & 63, rest = i >> 9;
        int ch = rest & 1, nt = rest >> 1;
        int k = ch * 32 + 8 * (l >> 4) + j;          // k = kk*4 + ci
        int co = nt * 16 + (l & 15);
        wB1[i] = f2bf(k < 36 ? w1[co * 36 + (k & 3) * 9 + (k >> 2)] : 0.0f);
    }
    if (i < 9216) {              // wB2/3/4[nt][kk][lane][j], k = kk*32 + ci
        int j = i & 7, l = (i >> 3) & 63, rest = i >> 9;
        int kk = rest % 9, nt = rest / 9;
        int ci = 8 * (l >> 4) + j, co = nt * 16 + (l & 15);
        wB2[i] = f2bf(w2[co * 288 + ci * 9 + kk]);
        wB3[i] = f2bf(w3[co * 288 + ci * 9 + kk]);
        wB4[i] = f2bf(w4[co * 288 + ci * 9 + kk]);
    }
    if (i < 884736) {            // wihF[ch(36)][st(48)][lane][j]
        int j = i & 7, l = (i >> 3) & 63, rest = i >> 9;
        int st = rest % 48, ch = rest / 48;
        int k = ch * 32 + 8 * (l >> 4) + j, n = st * 16 + (l & 15);
        wihF[i] = f2bf(W_ih[(size_t)n * FEAT + k]);
    }
    if (i < 196608) {            // whh16 flat bf16 copy, [g][k] row-major
        whh16[i] = f2bf(W_hh[i]);
    }
    if (i < G3) biasg[i] = b_ih[i] + (i < 2 * HID ? b_hh[i] : 0.0f);
}

// ============================================================================
// conv1: [CH,4,84,84] f32 -> x1 [CH,42,42,32] bf16 channel-last. K=36 pad 64.
// ============================================================================
__global__ __launch_bounds__(256) void conv1_kernel(
    const float* __restrict__ in, int n0,
    const bf16* __restrict__ wB1g, const float* __restrict__ b1,
    bf16* __restrict__ x1)
{
    __shared__ bf16 ins[7 * 84 * 4];   // [r][x][ci]
    __shared__ bf16 A[64 * 72];        // KP1 = 72 (64 + 8 pad)
    __shared__ bf16 wBs[2048];
    int tid = threadIdx.x;
    int nl = blockIdx.x / 28, blk = blockIdx.x % 28;
    int n = n0 + nl;
    int p0 = blk * 64;
    int oy_lo = p0 / 42;
    int oy_hi = (p0 + 63) / 42; if (oy_hi > 41) oy_hi = 41;
    int y_lo = 2 * oy_lo - 1;
    int rows = 2 * oy_hi + 2 - y_lo;   // <= 7

    if (tid < 256) ((uint4*)wBs)[tid] = ((const uint4*)wB1g)[tid];
    const float* inb = in + (size_t)n * 4 * 7056;
    for (int i = tid; i < rows * 336; i += 256) {
        int r = i / 336, rem = i % 336, ci = rem / 84, x = rem % 84;
        int y = y_lo + r;
        float v = (y >= 0) ? inb[ci * 7056 + y * 84 + x] : 0.0f;
        ins[(r * 84 + x) * 4 + ci] = f2bf(v);
    }
    __syncthreads();
    for (int i = tid; i < 576; i += 256) {
        int m = i / 9, q = i % 9;
        uint2 z; z.x = 0u; z.y = 0u;
        *(uint2*)&A[m * 72 + 36 + q * 4] = z;
    }
    for (int i = tid; i < 576; i += 256) {
        int m = i / 9, kk = i % 9;
        int kh = kk / 3, kw = kk - kh * 3;
        int p = p0 + m;
        uint2 v; v.x = 0u; v.y = 0u;
        if (p < 1764) {
            int oy = p / 42, ox = p - oy * 42;
            int y = 2 * oy - 1 + kh, x = 2 * ox - 1 + kw;
            if ((unsigned)y < 84u && (unsigned)x < 84u)
                v = *(const uint2*)&ins[((y - y_lo) * 84 + x) * 4];
        }
        *(uint2*)&A[m * 72 + kk * 4] = v;
    }
    __syncthreads();
    int lane = tid & 63, g = tid >> 6, quad = lane >> 4, c16 = lane & 15;
    int ma = g * 16 + c16;
    short8 a0 = *(const short8*)&A[ma * 72 + quad * 8];
    short8 a1 = *(const short8*)&A[ma * 72 + 32 + quad * 8];
    #pragma unroll
    for (int nt = 0; nt < 2; nt++) {
        float bv = b1[nt * 16 + c16];
        f32x4 acc = {bv, bv, bv, bv};
        short8 b0 = *(const short8*)&wBs[((nt * 2 + 0) * 64 + lane) * 8];
        short8 bq = *(const short8*)&wBs[((nt * 2 + 1) * 64 + lane) * 8];
        acc = MFMA(a0, b0, acc);
        acc = MFMA(a1, bq, acc);
        #pragma unroll
        for (int r = 0; r < 4; r++) {
            int p = p0 + g * 16 + 4 * quad + r;
            if (p < 1764) {
                float v = acc[r];
                v = v > 0.0f ? v : expm1f(v);
                x1[((size_t)nl * 1764 + p) * 32 + nt * 16 + c16] = f2bf(v);
            }
        }
    }
}

// ============================================================================
// convN (conv2/3/4): channel-last bf16 in, 3x3 s2 p1, Cin=Cout=32, K=288.
// ============================================================================
template<int HI, int HO, int OUTMODE>
__global__ __launch_bounds__(256) void convN_kernel(
    const bf16* __restrict__ xin, bf16* __restrict__ xout,
    const bf16* __restrict__ wBg, const float* __restrict__ bias, int n0)
{
    constexpr int NPIX = HO * HO;
    constexpr int NBLK = (NPIX + 63) / 64;
    __shared__ bf16 A[64 * 296];       // 37,888 B
    __shared__ bf16 wBs[9216];         // 18,432 B
    int tid = threadIdx.x;
    int nl = blockIdx.x / NBLK, blk = blockIdx.x % NBLK;
    int p0 = blk * 64;
    for (int i = tid; i < 1152; i += 256) ((uint4*)wBs)[i] = ((const uint4*)wBg)[i];
    const bf16* xb = xin + (size_t)nl * HI * HI * 32;
    for (int i = tid; i < 2304; i += 256) {
        int m = i / 36, t = i % 36, kk = t >> 2, part = t & 3;
        int kh = kk / 3, kw = kk - kh * 3;
        int p = p0 + m;
        uint4 v; v.x = v.y = v.z = v.w = 0u;
        if (p < NPIX) {
            int oy = p / HO, ox = p - oy * HO;
            int y = 2 * oy - 1 + kh, x = 2 * ox - 1 + kw;
            if ((unsigned)y < (unsigned)HI && (unsigned)x < (unsigned)HI)
                v = *(const uint4*)&xb[((size_t)(y * HI + x)) * 32 + part * 8];
        }
        *(uint4*)&A[m * 296 + kk * 32 + part * 8] = v;
    }
    __syncthreads();
    int lane = tid & 63, g = tid >> 6, quad = lane >> 4, c16 = lane & 15;
    int ma = g * 16 + c16;
    short8 af[9];
    #pragma unroll
    for (int kk = 0; kk < 9; kk++)
        af[kk] = *(const short8*)&A[ma * 296 + kk * 32 + quad * 8];
    #pragma unroll
    for (int nt = 0; nt < 2; nt++) {
        float bv = bias[nt * 16 + c16];
        f32x4 acc = {bv, bv, bv, bv};
        #pragma unroll
        for (int kk = 0; kk < 9; kk++) {
            short8 bfr = *(const short8*)&wBs[((nt * 9 + kk) * 64 + lane) * 8];
            acc = MFMA(af[kk], bfr, acc);
        }
        #pragma unroll
        for (int r = 0; r < 4; r++) {
            int p = p0 + g * 16 + 4 * quad + r;
            if (p < NPIX) {
                float v = acc[r];
                v = v > 0.0f ? v : expm1f(v);
                if (OUTMODE == 0)
                    xout[(((size_t)(n0 + nl)) * NPIX + p) * 32 + nt * 16 + c16] = f2bf(v);
                else
                    xout[(size_t)(n0 + nl) * FEAT + (nt * 16 + c16) * 36 + p] = f2bf(v);
            }
        }
    }
}

// ============================================================================
// GI = x4 @ W_ih^T + biasg : [2048,1152]bf16 x [1152,768] -> f32. MFMA.
// ============================================================================
__global__ __launch_bounds__(256) void gemm_gi_kernel(
    const bf16* __restrict__ X, const bf16* __restrict__ wihF,
    const float* __restrict__ biasg, float* __restrict__ GI)
{
    __shared__ bf16 As[64 * 40];
    int tid = threadIdx.x;
    int m0 = blockIdx.x * 64, nb = blockIdx.y * 4, n0 = blockIdx.y * 64;
    int lane = tid & 63, g = tid >> 6, quad = lane >> 4, c16 = lane & 15;
    f32x4 acc[4];
    #pragma unroll
    for (int st = 0; st < 4; st++) {
        float bv = biasg[n0 + st * 16 + c16];
        acc[st] = (f32x4){bv, bv, bv, bv};
    }
    int sm = tid >> 2, sp = tid & 3;
    for (int ch = 0; ch < 36; ch++) {
        __syncthreads();
        *(uint4*)&As[sm * 40 + sp * 8] =
            *(const uint4*)&X[(size_t)(m0 + sm) * FEAT + ch * 32 + sp * 8];
        __syncthreads();
        short8 af = *(const short8*)&As[(g * 16 + c16) * 40 + quad * 8];
        #pragma unroll
        for (int st = 0; st < 4; st++) {
            short8 bfr = *(const short8*)&wihF[(((size_t)ch * 48 + nb + st) * 64 + lane) * 8];
            acc[st] = MFMA(af, bfr, acc[st]);
        }
    }
    #pragma unroll
    for (int st = 0; st < 4; st++)
        #pragma unroll
        for (int r = 0; r < 4; r++)
            GI[(size_t)(m0 + g * 16 + 4 * quad + r) * G3 + n0 + st * 16 + c16] = acc[st][r];
}

// ============================================================================
// GRU scan: 32 blocks x 768 threads (one per gate-column).
// W_hh row (256 bf16 = 512B) held in 32 INDIVIDUALLY-NAMED uint4 locals
// (named scalars -> SSA -> guaranteed VGPRs; a uint4[32] array was demoted
// to scratch by the alloca-promotion heuristic in round 4: VGPR_Count=84).
// Step loop: 64 wave-uniform broadcast ds_read_b128 + 512 VALU, zero memory.
// ============================================================================
#define WDECL(i) uint4 w##i = wrow[i];
#define WDOT(i)  { uint4 w = w##i;                                             \
    float4 h0 = *(const float4*)&hs[(i) * 8];                                  \
    float4 h1 = *(const float4*)&hs[(i) * 8 + 4];                              \
    acc = fmaf(h0.x, __uint_as_float(w.x << 16), acc);                         \
    acc = fmaf(h0.y, __uint_as_float(w.x & 0xffff0000u), acc);                 \
    acc = fmaf(h0.z, __uint_as_float(w.y << 16), acc);                         \
    acc = fmaf(h0.w, __uint_as_float(w.y & 0xffff0000u), acc);                 \
    acc = fmaf(h1.x, __uint_as_float(w.z << 16), acc);                         \
    acc = fmaf(h1.y, __uint_as_float(w.z & 0xffff0000u), acc);                 \
    acc = fmaf(h1.z, __uint_as_float(w.w << 16), acc);                         \
    acc = fmaf(h1.w, __uint_as_float(w.w & 0xffff0000u), acc); }

__global__ __launch_bounds__(768, 3) void scan_kernel(
    const float* __restrict__ GI, const bf16* __restrict__ whh16,
    const float* __restrict__ b_hh, const float* __restrict__ rnn_in,
    const float* __restrict__ mask, float* __restrict__ H)
{
    __shared__ float hs[HID];
    __shared__ float pr[HID];
    __shared__ float pz[HID];
    __shared__ float pn[HID];
    int b = blockIdx.x, t = threadIdx.x;
    int gate = t >> 8, j = t & 255;

    const uint4* wrow = (const uint4*)(whh16 + (size_t)t * HID);
    WDECL(0)  WDECL(1)  WDECL(2)  WDECL(3)  WDECL(4)  WDECL(5)  WDECL(6)  WDECL(7)
    WDECL(8)  WDECL(9)  WDECL(10) WDECL(11) WDECL(12) WDECL(13) WDECL(14) WDECL(15)
    WDECL(16) WDECL(17) WDECL(18) WDECL(19) WDECL(20) WDECL(21) WDECL(22) WDECL(23)
    WDECL(24) WDECL(25) WDECL(26) WDECL(27) WDECL(28) WDECL(29) WDECL(30) WDECL(31)

    float bhn = (gate == 2) ? b_hh[2 * HID + j] : 0.0f;
    if (t < HID) hs[t] = rnn_in[b * HID + t] * mask[b];
    __syncthreads();

    for (int step = 0; step < TT; step++) {
        int row = step * BB + b;
        // combiner-thread prefetches (issued before the dot, consumed after barrier)
        float gr = 0.f, gz = 0.f, gn = 0.f, hold = 0.f, mnext = 1.0f;
        if (gate == 0) {
            const float* gp = GI + (size_t)row * G3 + j;
            gr = gp[0]; gz = gp[256]; gn = gp[512];
            hold = hs[j];
            if (step + 1 < TT) mnext = mask[(step + 1) * BB + b];
        }
        float acc = bhn;
        WDOT(0)  WDOT(1)  WDOT(2)  WDOT(3)  WDOT(4)  WDOT(5)  WDOT(6)  WDOT(7)
        WDOT(8)  WDOT(9)  WDOT(10) WDOT(11) WDOT(12) WDOT(13) WDOT(14) WDOT(15)
        WDOT(16) WDOT(17) WDOT(18) WDOT(19) WDOT(20) WDOT(21) WDOT(22) WDOT(23)
        WDOT(24) WDOT(25) WDOT(26) WDOT(27) WDOT(28) WDOT(29) WDOT(30) WDOT(31)
        if (gate == 0)      pr[j] = acc;
        else if (gate == 1) pz[j] = acc;
        else                pn[j] = acc;
        __syncthreads();
        if (gate == 0) {
            float r = 1.0f / (1.0f + expf(-(gr + pr[j])));
            float z = 1.0f / (1.0f + expf(-(gz + pz[j])));
            float pre = gn + r * pn[j];
            pre = fminf(15.0f, fmaxf(-15.0f, pre));
            float e = expf(2.0f * pre);
            float nn = (e - 1.0f) / (e + 1.0f);
            float hnew = (1.0f - z) * nn + z * hold;
            H[(size_t)row * HID + j] = hnew;
            hs[j] = hnew * mnext;
        }
        __syncthreads();
    }
}

// ---------------- heads: v, actions, logp_a, ent (float32 out) ----------------
__global__ __launch_bounds__(256) void heads_kernel(
    const float* __restrict__ H, const int* __restrict__ actions,
    const float* __restrict__ Wc, const float* __restrict__ bc,
    const float* __restrict__ Wa, const float* __restrict__ ba,
    float* __restrict__ out)
{
    int r = blockIdx.x * 256 + threadIdx.x;
    if (r >= NB) return;
    const float* h = H + (size_t)r * HID;
    float v = bc[0];
    for (int k = 0; k < HID; k++) v += h[k] * Wc[k];
    float lg[NA];
    for (int a = 0; a < NA; a++) {
        float s = ba[a];
        const float* wa = Wa + a * HID;
        for (int k = 0; k < HID; k++) s += h[k] * wa[k];
        lg[a] = s;
    }
    float mx = lg[0];
    for (int a = 1; a < NA; a++) mx = fmaxf(mx, lg[a]);
    float Z = 0.f;
    for (int a = 0; a < NA; a++) Z += expf(lg[a] - mx);
    float lse = mx + logf(Z);
    int act = actions[r];
    float logp_a = lg[act] - lse;
    float ent = 0.f;
    for (int a = 0; a < NA; a++) {
        float lp = lg[a] - lse;
        ent -= expf(lp) * lp;
    }
    out[r]          = v;
    out[NB + r]     = (float)act;
    out[2 * NB + r] = logp_a;
    out[3 * NB + r] = ent;
}

__global__ __launch_bounds__(256) void hfin_kernel(const float* __restrict__ H, float* __restrict__ out)
{
    int i = blockIdx.x * 256 + threadIdx.x;
    if (i < BB * HID)
        out[4 * NB + i] = H[(size_t)(TT - 1) * BB * HID + i];
}

extern "C" void kernel_launch(void* const* d_in, const int* in_sizes, int n_in,
                              void* d_out, int out_size, void* d_ws, size_t ws_size,
                              hipStream_t stream) {
    const float* inputs  = (const float*)d_in[0];
    const float* rnn_in  = (const float*)d_in[1];
    const float* mask    = (const float*)d_in[2];
    const int*   actions = (const int*)d_in[3];
    const float* w1 = (const float*)d_in[4];
    const float* b1 = (const float*)d_in[5];
    const float* w2 = (const float*)d_in[6];
    const float* b2 = (const float*)d_in[7];
    const float* w3 = (const float*)d_in[8];
    const float* b3 = (const float*)d_in[9];
    const float* w4 = (const float*)d_in[10];
    const float* b4 = (const float*)d_in[11];
    const float* W_ih = (const float*)d_in[12];
    const float* W_hh = (const float*)d_in[13];
    const float* b_ih = (const float*)d_in[14];
    const float* b_hh = (const float*)d_in[15];
    const float* Wc = (const float*)d_in[16];
    const float* bc = (const float*)d_in[17];
    const float* Wa = (const float*)d_in[18];
    const float* ba = (const float*)d_in[19];
    float* out = (float*)d_out;

    char* ws = (char*)d_ws;
    size_t o = 0;
    auto nxt = [&](size_t b) { void* p = ws + o; o += (b + 255) & ~(size_t)255; return p; };
    bf16* wB1  = (bf16*)nxt(2048 * 2);
    bf16* wB2  = (bf16*)nxt(9216 * 2);
    bf16* wB3  = (bf16*)nxt(9216 * 2);
    bf16* wB4  = (bf16*)nxt(9216 * 2);
    bf16* wihF = (bf16*)nxt(884736 * 2);
    bf16* whh16 = (bf16*)nxt(196608 * 2);
    float* biasg = (float*)nxt(768 * 4);
    bf16* x4 = (bf16*)nxt((size_t)NB * FEAT * 2);            //  4.72 MB
    bf16* x2 = (bf16*)nxt((size_t)NB * 441 * 32 * 2);        // 57.80 MB

    // dynamic conv1/conv2 chunking based on available workspace
    const size_t X1_PER_IMG = 1764 * 32 * 2;                  // 112,896 B
    const size_t TAILFIX = 15859712 + 6291456 + 2097152 + 1024; // x3+GI+H
    bf16* x3; float* GI; float* H; bf16* x1c;
    int CH;
    if (ws_size >= o + TAILFIX + 2048 * X1_PER_IMG + (1u << 20)) {
        CH = 2048;
        x3 = (bf16*)nxt(15859712); GI = (float*)nxt(6291456); H = (float*)nxt(2097152);
        x1c = (bf16*)nxt(2048 * X1_PER_IMG);
    } else if (ws_size >= o + TAILFIX + 512 * X1_PER_IMG + (1u << 20)) {
        CH = 512;
        x3 = (bf16*)nxt(15859712); GI = (float*)nxt(6291456); H = (float*)nxt(2097152);
        x1c = (bf16*)nxt(512 * X1_PER_IMG);
    } else if (ws_size >= o + TAILFIX + 256 * X1_PER_IMG + (1u << 20)) {
        CH = 256;
        x3 = (bf16*)nxt(15859712); GI = (float*)nxt(6291456); H = (float*)nxt(2097152);
        x1c = (bf16*)nxt(256 * X1_PER_IMG);
    } else {
        // known-good overlay layout (93.7 MB total): x1c shares region with x3/GI/H
        CH = 256;
        char* R1 = (char*)nxt(28901376);
        x1c = (bf16*)R1;
        x3  = (bf16*)R1;
        GI  = (float*)(R1 + 15859712);
        H   = (float*)(R1 + 15859712 + 6291456);
    }

    prep_kernel<<<3456, 256, 0, stream>>>(w1, w2, w3, w4, W_ih, W_hh, b_ih, b_hh,
                                          wB1, wB2, wB3, wB4, wihF, whh16, biasg);
    for (int c = 0; c < 2048 / CH; c++) {
        conv1_kernel<<<CH * 28, 256, 0, stream>>>(inputs, c * CH, wB1, b1, x1c);
        convN_kernel<42, 21, 0><<<CH * 7, 256, 0, stream>>>(x1c, x2, wB2, b2, c * CH);
    }
    convN_kernel<21, 11, 0><<<2048 * 2, 256, 0, stream>>>(x2, x3, wB3, b3, 0);
    convN_kernel<11, 6, 1><<<2048, 256, 0, stream>>>(x3, x4, wB4, b4, 0);
    gemm_gi_kernel<<<dim3(32, 12), 256, 0, stream>>>(x4, wihF, biasg, GI);
    scan_kernel<<<BB, 768, 0, stream>>>(GI, whh16, b_hh, rnn_in, mask, H);
    heads_kernel<<<NB / 256, 256, 0, stream>>>(H, actions, Wc, bc, Wa, ba, out);
    hfin_kernel<<<(BB * HID + 255) / 256, 256, 0, stream>>>(H, out);
}